// Round 10
// baseline (85.749 us; speedup 1.0000x reference)
//
#include <hip/hip_runtime.h>
#include <hip/hip_fp16.h>
#include <cstdint>
#include <cstddef>

// FastGRNN cell, MI355X fp16-MFMA, v10.
// prep:   weights f32->f16 into wb.
// stage1: STAGE2-CLONE shape: 1536 blocks x 256 thr, BM=64 BN=128 K=512 (8 it),
//         24KB LDS, plain __syncthreads 1-deep prefetch. 6 K-split panels
//         (x: 2, h: 4) -> rb6[8192][1536] f16.
// reduce: rb6 -> rb2[8192][512] (wx = p0+p1, uh = p2+..+p5), deterministic.
// stage2: pre = rb2 @ [W2|U2]^T (K=512) + fused sigmoid/tanh epilogue.

typedef _Float16 half8 __attribute__((ext_vector_type(8)));
typedef float f32x4 __attribute__((ext_vector_type(4)));

#define DIN 1024
#define DH 2048
#define RK 256
#define RB6LD 1536
// wb half-offsets
#define OFF_W1H 0
#define OFF_U1H 262144
#define OFF_W2H 786432
#define OFF_U2H 1310720
#define WB_HALVES 1835008

__device__ __forceinline__ half8 cvt8(const float4 a, const float4 b) {
  half8 h;
  h[0] = (_Float16)a.x; h[1] = (_Float16)a.y; h[2] = (_Float16)a.z; h[3] = (_Float16)a.w;
  h[4] = (_Float16)b.x; h[5] = (_Float16)b.y; h[6] = (_Float16)b.z; h[7] = (_Float16)b.w;
  return h;
}

// ---------------- prep: weights f32 -> f16 ----------------------------------
__global__ __launch_bounds__(256)
void fgrnn_prep(const float* __restrict__ W1, const float* __restrict__ U1,
                const float* __restrict__ W2, const float* __restrict__ U2,
                _Float16* __restrict__ wb) {
  const int q = blockIdx.x * 256 + threadIdx.x;
  const float* src;
  int rel;
  if (q < 65536) { src = W1; rel = q; }
  else if (q < 196608) { src = U1; rel = q - 65536; }
  else if (q < 327680) { src = W2; rel = q - 196608; }
  else { src = U2; rel = q - 327680; }
  const float4 v = reinterpret_cast<const float4*>(src)[rel];
  union { _Float16 h[4]; uint2 u; } cv;
  cv.h[0] = (_Float16)v.x; cv.h[1] = (_Float16)v.y;
  cv.h[2] = (_Float16)v.z; cv.h[3] = (_Float16)v.w;
  reinterpret_cast<uint2*>(wb)[q] = cv.u;
}

// ---------------- stage 1: stage2-clone GEMM, 6 K-split panels --------------
// 1536 blocks x 256 thr. BM=64, BN=128, BK=64, 8 iters. 4 waves 2x2,
// wave tile 32x64 (acc[2][4]). panel p: p<2 -> x@W1^T kslice p;
// p>=2 -> h@U1^T kslice p-2. ncol picks weight rows ncol*128..+128.
__global__ __launch_bounds__(256)
void fgrnn_stage1(const float* __restrict__ x, const float* __restrict__ h,
                  const _Float16* __restrict__ wb, _Float16* __restrict__ rb6) {
  const int bid = blockIdx.x;
  const int L = (bid & 7) * 192 + (bid >> 3);  // XCD chunk swizzle (1536=8*192)
  const int p = L >> 8;                        // 0..5 panel
  const int rem = L & 255;
  const int ncol = rem >> 7;                   // 0,1
  const int mtile = rem & 127;                 // 0..127
  const bool isx = (p < 2);
  const float* A = isx ? x : h;
  const int KA = isx ? DIN : DH;
  const int kbase = (isx ? p : (p - 2)) * 512;
  const _Float16* Bw = wb + (isx ? OFF_W1H : OFF_U1H) + (size_t)(ncol * 128) * KA;
  const int row0 = mtile * 64;
  const int colbase = p * 256 + ncol * 128;

  __shared__ _Float16 As[64 * 64];    // 8 KB  (XOR swizzle: c ^= (r&7)<<3)
  __shared__ _Float16 Bs[128 * 64];   // 16 KB

  const int tid = threadIdx.x;
  const int lane = tid & 63;
  const int w = tid >> 6;
  const int wr = w >> 1, wc = w & 1;

  f32x4 acc[2][4];
#pragma unroll
  for (int i = 0; i < 2; ++i)
#pragma unroll
    for (int j = 0; j < 4; ++j) acc[i][j] = (f32x4){0.f, 0.f, 0.f, 0.f};

  const int sr = tid >> 3;      // 0..31
  const int sc = (tid & 7) * 8;

  float4 pa4[2][2];
  half8 pb[4];

  auto LOADG = [&](int it) {
    const int k0 = kbase + it * 64;
#pragma unroll
    for (int j = 0; j < 2; ++j) {
      const float* s = A + (size_t)(row0 + j * 32 + sr) * KA + k0 + sc;
      pa4[j][0] = *reinterpret_cast<const float4*>(s);
      pa4[j][1] = *reinterpret_cast<const float4*>(s + 4);
    }
#pragma unroll
    for (int j = 0; j < 4; ++j)
      pb[j] = *reinterpret_cast<const half8*>(Bw + (size_t)(j * 32 + sr) * KA + k0 + sc);
  };
  auto STORE = [&]() {
#pragma unroll
    for (int j = 0; j < 2; ++j) {
      const int r = j * 32 + sr;
      *reinterpret_cast<half8*>(&As[r * 64 + (sc ^ ((r & 7) << 3))]) =
          cvt8(pa4[j][0], pa4[j][1]);
    }
#pragma unroll
    for (int j = 0; j < 4; ++j) {
      const int r = j * 32 + sr;
      *reinterpret_cast<half8*>(&Bs[r * 64 + (sc ^ ((r & 7) << 3))]) = pb[j];
    }
  };

  LOADG(0);
  STORE();
  __syncthreads();

  for (int it = 0; it < 8; ++it) {
    const bool more = (it + 1 < 8);
    if (more) LOADG(it + 1);
#pragma unroll
    for (int kk = 0; kk < 64; kk += 32) {
      half8 af[2], bf[4];
#pragma unroll
      for (int mi = 0; mi < 2; ++mi) {
        const int r = wr * 32 + mi * 16 + (lane & 15);
        af[mi] = *reinterpret_cast<const half8*>(
            &As[r * 64 + ((kk + 8 * (lane >> 4)) ^ ((r & 7) << 3))]);
      }
#pragma unroll
      for (int ni = 0; ni < 4; ++ni) {
        const int r = wc * 64 + ni * 16 + (lane & 15);
        bf[ni] = *reinterpret_cast<const half8*>(
            &Bs[r * 64 + ((kk + 8 * (lane >> 4)) ^ ((r & 7) << 3))]);
      }
#pragma unroll
      for (int mi = 0; mi < 2; ++mi)
#pragma unroll
        for (int ni = 0; ni < 4; ++ni)
          acc[mi][ni] =
              __builtin_amdgcn_mfma_f32_16x16x32_f16(af[mi], bf[ni], acc[mi][ni], 0, 0, 0);
    }
    if (more) {
      __syncthreads();
      STORE();
    }
    __syncthreads();
  }

  // D layout (16x16 family): row = 4*(lane>>4)+e, col = lane&15.
#pragma unroll
  for (int mi = 0; mi < 2; ++mi)
#pragma unroll
    for (int ni = 0; ni < 4; ++ni)
#pragma unroll
      for (int e = 0; e < 4; ++e) {
        const int row = row0 + wr * 32 + mi * 16 + 4 * (lane >> 4) + e;
        const int col = colbase + wc * 64 + ni * 16 + (lane & 15);
        rb6[(size_t)row * RB6LD + col] = (_Float16)acc[mi][ni][e];
      }
}

// ---------------- reduce: rb6[8192][1536] -> rb2[8192][512] -----------------
// Deterministic fixed-order panel sums. 2048 blocks x 256 thr; one half8 each.
__global__ __launch_bounds__(256)
void fgrnn_reduce(const _Float16* __restrict__ rb6, _Float16* __restrict__ rb2) {
  const int t = blockIdx.x * 256 + threadIdx.x;  // 0..524287
  const int row = t >> 6;
  const int ch = t & 63;
  const _Float16* src = rb6 + (size_t)row * RB6LD;
  half8 s;
  int outcol;
  if (ch < 32) {  // wx = p0 + p1
    const int c = ch * 8;
    s = *reinterpret_cast<const half8*>(src + c) +
        *reinterpret_cast<const half8*>(src + 256 + c);
    outcol = c;
  } else {        // uh = p2 + p3 + p4 + p5
    const int c = (ch - 32) * 8;
    const _Float16* su = src + 512;
    s = *reinterpret_cast<const half8*>(su + c) +
        *reinterpret_cast<const half8*>(su + 256 + c);
    s = s + *reinterpret_cast<const half8*>(su + 512 + c);
    s = s + *reinterpret_cast<const half8*>(su + 768 + c);
    outcol = 256 + c;
  }
  *reinterpret_cast<half8*>(rb2 + (size_t)row * 512 + outcol) = s;
}

// ---------------- stage 2: pre = rb2 @ [W2|U2]^T, K=512 ---------------------
// 2048 blocks x 256 threads. BM=64, BN=128, BK=64, 8 iters; 4 waves 2x2.
__global__ __launch_bounds__(256)
void fgrnn_stage2(const _Float16* __restrict__ rb2, const _Float16* __restrict__ wb,
                  const float* __restrict__ state,
                  const float* __restrict__ bg, const float* __restrict__ bu,
                  const float* __restrict__ zeta, const float* __restrict__ nu,
                  float* __restrict__ out) {
  const int bid = blockIdx.x;
  const int L = (bid & 7) * 256 + (bid >> 3);   // XCD swizzle: mtile-banded
  const int mtile = L >> 4;   // 0..127
  const int ntile = L & 15;   // 0..15
  const int row0 = mtile * 64;
  const int col0 = ntile * 128;
  const _Float16* W2h = wb + OFF_W2H;
  const _Float16* U2h = wb + OFF_U2H;

  __shared__ _Float16 As[64 * 64];
  __shared__ _Float16 Bs[128 * 64];

  const int tid = threadIdx.x;
  const int lane = tid & 63;
  const int w = tid >> 6;
  const int wr = w >> 1, wc = w & 1;

  f32x4 acc[2][4];
#pragma unroll
  for (int i = 0; i < 2; ++i)
#pragma unroll
    for (int j = 0; j < 4; ++j) acc[i][j] = (f32x4){0.f, 0.f, 0.f, 0.f};

  const int sr = tid >> 3;      // 0..31
  const int sc = (tid & 7) * 8;

  half8 pa[2], pb[4];

  auto LOADG = [&](int it) {
    const int k0 = it * 64;
#pragma unroll
    for (int j = 0; j < 2; ++j)
      pa[j] = *reinterpret_cast<const half8*>(rb2 + (size_t)(row0 + j * 32 + sr) * 512 + k0 + sc);
    const _Float16* Bh = (k0 < 256) ? W2h : U2h;
    const int kb = k0 & 255;
#pragma unroll
    for (int j = 0; j < 4; ++j)
      pb[j] = *reinterpret_cast<const half8*>(Bh + (size_t)(col0 + j * 32 + sr) * RK + kb + sc);
  };
  auto STORE = [&]() {
#pragma unroll
    for (int j = 0; j < 2; ++j) {
      const int r = j * 32 + sr;
      *reinterpret_cast<half8*>(&As[r * 64 + (sc ^ ((r & 7) << 3))]) = pa[j];
    }
#pragma unroll
    for (int j = 0; j < 4; ++j) {
      const int r = j * 32 + sr;
      *reinterpret_cast<half8*>(&Bs[r * 64 + (sc ^ ((r & 7) << 3))]) = pb[j];
    }
  };

  LOADG(0);
  STORE();
  __syncthreads();

  for (int it = 0; it < 8; ++it) {
    const bool more = (it + 1 < 8);
    if (more) LOADG(it + 1);
#pragma unroll
    for (int kk = 0; kk < 64; kk += 32) {
      half8 af[2], bf[4];
#pragma unroll
      for (int mi = 0; mi < 2; ++mi) {
        const int r = wr * 32 + mi * 16 + (lane & 15);
        af[mi] = *reinterpret_cast<const half8*>(
            &As[r * 64 + ((kk + 8 * (lane >> 4)) ^ ((r & 7) << 3))]);
      }
#pragma unroll
      for (int ni = 0; ni < 4; ++ni) {
        const int r = wc * 64 + ni * 16 + (lane & 15);
        bf[ni] = *reinterpret_cast<const half8*>(
            &Bs[r * 64 + ((kk + 8 * (lane >> 4)) ^ ((r & 7) << 3))]);
      }
#pragma unroll
      for (int mi = 0; mi < 2; ++mi)
#pragma unroll
        for (int ni = 0; ni < 4; ++ni)
          acc[mi][ni] =
              __builtin_amdgcn_mfma_f32_16x16x32_f16(af[mi], bf[ni], acc[mi][ni], 0, 0, 0);
    }
    if (more) {
      __syncthreads();
      STORE();
    }
    __syncthreads();
  }

  // Fused epilogue (fast exp2/rcp; asymptotes correct)
  const float LOG2E = 1.44269504f;
  const float sz = __builtin_amdgcn_rcpf(1.f + __builtin_amdgcn_exp2f(-zeta[0] * LOG2E));
  const float sn = __builtin_amdgcn_rcpf(1.f + __builtin_amdgcn_exp2f(-nu[0] * LOG2E));
#pragma unroll
  for (int mi = 0; mi < 2; ++mi)
#pragma unroll
    for (int ni = 0; ni < 4; ++ni) {
      const int col = col0 + wc * 64 + ni * 16 + (lane & 15);
      const float bgc = bg[col];
      const float buc = bu[col];
#pragma unroll
      for (int e = 0; e < 4; ++e) {
        const int row = row0 + wr * 32 + mi * 16 + 4 * (lane >> 4) + e;
        const float pre = acc[mi][ni][e];
        const float zg =
            __builtin_amdgcn_rcpf(1.f + __builtin_amdgcn_exp2f(-(pre + bgc) * LOG2E));
        const float hc =
            1.f - 2.f * __builtin_amdgcn_rcpf(
                            1.f + __builtin_amdgcn_exp2f((pre + buc) * (2.f * LOG2E)));
        const float sv = state[(size_t)row * DH + col];
        out[(size_t)row * DH + col] = zg * sv + (sz * (1.f - zg) + sn) * hc;
      }
    }
}

extern "C" void kernel_launch(void* const* d_in, const int* in_sizes, int n_in,
                              void* d_out, int out_size, void* d_ws, size_t ws_size,
                              hipStream_t stream) {
  const float* input = (const float*)d_in[0];
  const float* state = (const float*)d_in[1];
  const float* W1 = (const float*)d_in[2];
  const float* W2 = (const float*)d_in[3];
  const float* U1 = (const float*)d_in[4];
  const float* U2 = (const float*)d_in[5];
  const float* bg = (const float*)d_in[6];
  const float* bu = (const float*)d_in[7];
  const float* zeta = (const float*)d_in[8];
  const float* nu = (const float*)d_in[9];
  float* out = (float*)d_out;

  _Float16* rb6 = (_Float16*)d_ws;                      // 8192*1536*2 = 25.2 MB
  _Float16* rb2 = rb6 + (size_t)8192 * RB6LD;           // 8.4 MB
  _Float16* wb = rb2 + (size_t)8192 * 512;              // 3.67 MB (37.3 MB total)

  fgrnn_prep<<<1792, 256, 0, stream>>>(W1, U1, W2, U2, wb);
  fgrnn_stage1<<<1536, 256, 0, stream>>>(input, state, wb, rb6);
  fgrnn_reduce<<<2048, 256, 0, stream>>>(rb6, rb2);
  fgrnn_stage2<<<2048, 256, 0, stream>>>(rb2, wb, state, bg, bu, zeta, nu, out);
}

// Round 11
// 78.539 us; speedup vs baseline: 1.0918x; 1.0918x over previous
//
#include <hip/hip_runtime.h>
#include <hip/hip_fp16.h>
#include <cstdint>
#include <cstddef>

// FastGRNN cell, MI355X fp16-MFMA, v11.
// prep:   W1,U1 -> f16 K-TILED [kchunk][256][128] (contiguous B staging);
//         W2,U2 -> f16 flat.
// stage1: 512 blocks x 512 thr (exactly 2/CU, one round). BK=128.
//         x-blocks (256): BM=32, BN=256, K=1024 -> rbuf cols 0..255.
//         h-blocks (256): BM=64, BN=256, K=1024-halves -> cols 256..511/512..767.
//         All VMEM streams near-contiguous (<=4 pages/instr vs old 8-16).
// stage2: pre = [wx | uh0+uh1] @ [W2|U2]^T (K=512), fused sigmoid/tanh epilogue.

typedef _Float16 half8 __attribute__((ext_vector_type(8)));
typedef float f32x4 __attribute__((ext_vector_type(4)));

#define DIN 1024
#define DH 2048
#define RK 256
#define RBLD 768
// wb half-offsets
#define OFF_W1T 0         // [8][256][128]
#define OFF_U1T 262144    // [16][256][128]
#define OFF_W2H 786432    // flat [2048][256]
#define OFF_U2H 1310720

__device__ __forceinline__ half8 cvt8(const float4 a, const float4 b) {
  half8 h;
  h[0] = (_Float16)a.x; h[1] = (_Float16)a.y; h[2] = (_Float16)a.z; h[3] = (_Float16)a.w;
  h[4] = (_Float16)b.x; h[5] = (_Float16)b.y; h[6] = (_Float16)b.z; h[7] = (_Float16)b.w;
  return h;
}

// ---------------- prep: weights f32 -> f16 (W1/U1 K-tiled) ------------------
__global__ __launch_bounds__(256)
void fgrnn_prep(const float* __restrict__ W1, const float* __restrict__ U1,
                const float* __restrict__ W2, const float* __restrict__ U2,
                _Float16* __restrict__ wb) {
  const int q = blockIdx.x * 256 + threadIdx.x;   // float4-quad index
  float4 v;
  int o;
  if (q < 65536) {                 // W1 [256][1024] -> [8][256][128]
    v = reinterpret_cast<const float4*>(W1)[q];
    const int e = q * 4, r = e >> 10, k = e & 1023;
    o = OFF_W1T + (k >> 7) * 32768 + r * 128 + (k & 127);
  } else if (q < 196608) {         // U1 [256][2048] -> [16][256][128]
    const int qq = q - 65536;
    v = reinterpret_cast<const float4*>(U1)[qq];
    const int e = qq * 4, r = e >> 11, k = e & 2047;
    o = OFF_U1T + (k >> 7) * 32768 + r * 128 + (k & 127);
  } else if (q < 327680) {         // W2 flat
    const int qq = q - 196608;
    v = reinterpret_cast<const float4*>(W2)[qq];
    o = OFF_W2H + qq * 4;
  } else {                         // U2 flat
    const int qq = q - 327680;
    v = reinterpret_cast<const float4*>(U2)[qq];
    o = OFF_U2H + qq * 4;
  }
  union { _Float16 hh[4]; uint2 u; } cv;
  cv.hh[0] = (_Float16)v.x; cv.hh[1] = (_Float16)v.y;
  cv.hh[2] = (_Float16)v.z; cv.hh[3] = (_Float16)v.w;
  *reinterpret_cast<uint2*>(wb + o) = cv.u;
}

// ---------------- stage 1: page-friendly staging, BK=128 --------------------
// Swizzle for [.][128]-f16 rows: col ^= (r&7)<<3 (proven 2-way-free pattern).
__global__ __launch_bounds__(512, 4)
void fgrnn_stage1(const float* __restrict__ x, const float* __restrict__ h,
                  const _Float16* __restrict__ wb, _Float16* __restrict__ rbuf) {
  __shared__ _Float16 As[64 * 128];    // 16 KB (x-blocks use 32 rows)
  __shared__ _Float16 Bs[256 * 128];   // 64 KB

  const int bid = blockIdx.x;
  const int L = (bid & 7) * 64 + (bid >> 3);   // XCD swizzle (512 = 8*64)
  const int tid = threadIdx.x;
  const int lane = tid & 63;
  const int wv = tid >> 6;

  if (L < 256) {
    // ======== x-block: BM=32, BN=256, K=1024 (8 iters of BK=128) ========
    const int row0 = L * 32;
    const _Float16* Wt = wb + OFF_W1T;

    f32x4 acc[2][2];
#pragma unroll
    for (int i = 0; i < 2; ++i)
#pragma unroll
      for (int j = 0; j < 2; ++j) acc[i][j] = (f32x4){0.f, 0.f, 0.f, 0.f};

    const int sr = tid >> 4;         // A row 0..31
    const int sg = (tid & 15) * 8;   // col within 128-chunk

    float4 pa0, pa1;
    half8 pbx[8];

    auto LOADG = [&](int it) {
      const float* s = x + (size_t)(row0 + sr) * DIN + it * 128 + sg;
      pa0 = *reinterpret_cast<const float4*>(s);
      pa1 = *reinterpret_cast<const float4*>(s + 4);
      const _Float16* bsrc = Wt + it * 32768 + tid * 8;   // pure sequential
#pragma unroll
      for (int i = 0; i < 8; ++i)
        pbx[i] = *reinterpret_cast<const half8*>(bsrc + i * 4096);
    };
    auto STORE = [&]() {
      *reinterpret_cast<half8*>(&As[sr * 128 + (sg ^ ((sr & 7) << 3))]) = cvt8(pa0, pa1);
#pragma unroll
      for (int i = 0; i < 8; ++i) {
        const int idx = tid + i * 512;
        const int r = idx >> 4, c = (idx & 15) * 8;
        *reinterpret_cast<half8*>(&Bs[r * 128 + (c ^ ((r & 7) << 3))]) = pbx[i];
      }
    };

    LOADG(0);
    STORE();
    __syncthreads();

    for (int it = 0; it < 8; ++it) {
      const bool more = (it + 1 < 8);
      if (more) LOADG(it + 1);
#pragma unroll
      for (int kk = 0; kk < 128; kk += 32) {
        half8 af[2], bf[2];
#pragma unroll
        for (int mi = 0; mi < 2; ++mi) {
          const int r = mi * 16 + (lane & 15);
          af[mi] = *reinterpret_cast<const half8*>(
              &As[r * 128 + ((kk + 8 * (lane >> 4)) ^ ((r & 7) << 3))]);
        }
#pragma unroll
        for (int ni = 0; ni < 2; ++ni) {
          const int r = wv * 32 + ni * 16 + (lane & 15);
          bf[ni] = *reinterpret_cast<const half8*>(
              &Bs[r * 128 + ((kk + 8 * (lane >> 4)) ^ ((r & 7) << 3))]);
        }
#pragma unroll
        for (int mi = 0; mi < 2; ++mi)
#pragma unroll
          for (int ni = 0; ni < 2; ++ni)
            acc[mi][ni] =
                __builtin_amdgcn_mfma_f32_16x16x32_f16(af[mi], bf[ni], acc[mi][ni], 0, 0, 0);
      }
      if (more) {
        __syncthreads();
        STORE();
      }
      __syncthreads();
    }

#pragma unroll
    for (int mi = 0; mi < 2; ++mi)
#pragma unroll
      for (int ni = 0; ni < 2; ++ni)
#pragma unroll
        for (int e = 0; e < 4; ++e) {
          const int row = row0 + mi * 16 + 4 * (lane >> 4) + e;
          const int col = wv * 32 + ni * 16 + (lane & 15);
          rbuf[(size_t)row * RBLD + col] = (_Float16)acc[mi][ni][e];
        }
  } else {
    // ======== h-block: BM=64, BN=256, K=1024-half (8 iters of BK=128) ========
    const int r6 = L - 256;          // 0..255
    const int kp = r6 >> 7;          // 0,1 k-panel
    const int mtile = r6 & 127;
    const int row0 = mtile * 64;
    const _Float16* Ut = wb + OFF_U1T + kp * 8 * 32768;
    const int kofs = kp * 1024;
    const int colbase = 256 + kp * 256;
    const int wr = wv >> 2, wc = wv & 3;

    f32x4 acc[2][4];
#pragma unroll
    for (int i = 0; i < 2; ++i)
#pragma unroll
      for (int j = 0; j < 4; ++j) acc[i][j] = (f32x4){0.f, 0.f, 0.f, 0.f};

    float4 pa0[2], pa1[2];
    half8 pbx[8];

    auto LOADG = [&](int it) {
#pragma unroll
      for (int j = 0; j < 2; ++j) {
        const int idx = tid + j * 512;
        const int r = idx >> 4, g = (idx & 15) * 8;
        const float* s = h + (size_t)(row0 + r) * DH + kofs + it * 128 + g;
        pa0[j] = *reinterpret_cast<const float4*>(s);
        pa1[j] = *reinterpret_cast<const float4*>(s + 4);
      }
      const _Float16* bsrc = Ut + it * 32768 + tid * 8;   // pure sequential
#pragma unroll
      for (int i = 0; i < 8; ++i)
        pbx[i] = *reinterpret_cast<const half8*>(bsrc + i * 4096);
    };
    auto STORE = [&]() {
#pragma unroll
      for (int j = 0; j < 2; ++j) {
        const int idx = tid + j * 512;
        const int r = idx >> 4, c = (idx & 15) * 8;
        *reinterpret_cast<half8*>(&As[r * 128 + (c ^ ((r & 7) << 3))]) =
            cvt8(pa0[j], pa1[j]);
      }
#pragma unroll
      for (int i = 0; i < 8; ++i) {
        const int idx = tid + i * 512;
        const int r = idx >> 4, c = (idx & 15) * 8;
        *reinterpret_cast<half8*>(&Bs[r * 128 + (c ^ ((r & 7) << 3))]) = pbx[i];
      }
    };

    LOADG(0);
    STORE();
    __syncthreads();

    for (int it = 0; it < 8; ++it) {
      const bool more = (it + 1 < 8);
      if (more) LOADG(it + 1);
#pragma unroll
      for (int kk = 0; kk < 128; kk += 32) {
        half8 af[2], bf[4];
#pragma unroll
        for (int mi = 0; mi < 2; ++mi) {
          const int r = wr * 32 + mi * 16 + (lane & 15);
          af[mi] = *reinterpret_cast<const half8*>(
              &As[r * 128 + ((kk + 8 * (lane >> 4)) ^ ((r & 7) << 3))]);
        }
#pragma unroll
        for (int ni = 0; ni < 4; ++ni) {
          const int r = wc * 64 + ni * 16 + (lane & 15);
          bf[ni] = *reinterpret_cast<const half8*>(
              &Bs[r * 128 + ((kk + 8 * (lane >> 4)) ^ ((r & 7) << 3))]);
        }
#pragma unroll
        for (int mi = 0; mi < 2; ++mi)
#pragma unroll
          for (int ni = 0; ni < 4; ++ni)
            acc[mi][ni] =
                __builtin_amdgcn_mfma_f32_16x16x32_f16(af[mi], bf[ni], acc[mi][ni], 0, 0, 0);
      }
      if (more) {
        __syncthreads();
        STORE();
      }
      __syncthreads();
    }

#pragma unroll
    for (int mi = 0; mi < 2; ++mi)
#pragma unroll
      for (int ni = 0; ni < 4; ++ni)
#pragma unroll
        for (int e = 0; e < 4; ++e) {
          const int row = row0 + wr * 32 + mi * 16 + 4 * (lane >> 4) + e;
          const int col = colbase + wc * 64 + ni * 16 + (lane & 15);
          rbuf[(size_t)row * RBLD + col] = (_Float16)acc[mi][ni][e];
        }
  }
}

// ---------------- stage 2: pre = [wx | uh0+uh1] @ [W2|U2]^T, K=512 ----------
// 2048 blocks x 256 threads. BM=64, BN=128, BK=64, 8 iters; 4 waves 2x2.
// (R8-verbatim; measured ~25 us.)
__global__ __launch_bounds__(256)
void fgrnn_stage2(const _Float16* __restrict__ rbuf, const _Float16* __restrict__ wb,
                  const float* __restrict__ state,
                  const float* __restrict__ bg, const float* __restrict__ bu,
                  const float* __restrict__ zeta, const float* __restrict__ nu,
                  float* __restrict__ out) {
  const int bid = blockIdx.x;
  const int L = (bid & 7) * 256 + (bid >> 3);   // XCD swizzle: mtile-banded
  const int mtile = L >> 4;   // 0..127
  const int ntile = L & 15;   // 0..15
  const int row0 = mtile * 64;
  const int col0 = ntile * 128;
  const _Float16* W2h = wb + OFF_W2H;
  const _Float16* U2h = wb + OFF_U2H;

  __shared__ _Float16 As[64 * 64];
  __shared__ _Float16 Bs[128 * 64];

  const int tid = threadIdx.x;
  const int lane = tid & 63;
  const int w = tid >> 6;
  const int wr = w >> 1, wc = w & 1;

  f32x4 acc[2][4];
#pragma unroll
  for (int i = 0; i < 2; ++i)
#pragma unroll
    for (int j = 0; j < 4; ++j) acc[i][j] = (f32x4){0.f, 0.f, 0.f, 0.f};

  const int sr = tid >> 3;      // 0..31
  const int sc = (tid & 7) * 8;

  half8 pa[2], pa2[2], pb[4];

  auto LOADG = [&](int it) {
    const int k0 = it * 64;
    const bool iswx = (k0 < 256);
#pragma unroll
    for (int j = 0; j < 2; ++j) {
      const _Float16* p = rbuf + (size_t)(row0 + j * 32 + sr) * RBLD + k0 + sc;
      pa[j] = *reinterpret_cast<const half8*>(p);
      if (!iswx) pa2[j] = *reinterpret_cast<const half8*>(p + 256);  // uh1 panel
    }
    const _Float16* Bh = iswx ? W2h : U2h;
    const int kb = k0 & 255;
#pragma unroll
    for (int j = 0; j < 4; ++j)
      pb[j] = *reinterpret_cast<const half8*>(Bh + (size_t)(col0 + j * 32 + sr) * RK + kb + sc);
  };
  auto STORE = [&](int it) {
    const int k0 = it * 64;
#pragma unroll
    for (int j = 0; j < 2; ++j) {
      half8 v = pa[j];
      if (k0 >= 256) v = v + pa2[j];   // uh = uh0 + uh1 (v_pk_add_f16)
      const int r = j * 32 + sr;
      *reinterpret_cast<half8*>(&As[r * 64 + (sc ^ ((r & 7) << 3))]) = v;
    }
#pragma unroll
    for (int j = 0; j < 4; ++j) {
      const int r = j * 32 + sr;
      *reinterpret_cast<half8*>(&Bs[r * 64 + (sc ^ ((r & 7) << 3))]) = pb[j];
    }
  };

  LOADG(0);
  STORE(0);
  __syncthreads();

  for (int it = 0; it < 8; ++it) {
    const bool more = (it + 1 < 8);
    if (more) LOADG(it + 1);
#pragma unroll
    for (int kk = 0; kk < 64; kk += 32) {
      half8 af[2], bf[4];
#pragma unroll
      for (int mi = 0; mi < 2; ++mi) {
        const int r = wr * 32 + mi * 16 + (lane & 15);
        af[mi] = *reinterpret_cast<const half8*>(
            &As[r * 64 + ((kk + 8 * (lane >> 4)) ^ ((r & 7) << 3))]);
      }
#pragma unroll
      for (int ni = 0; ni < 4; ++ni) {
        const int r = wc * 64 + ni * 16 + (lane & 15);
        bf[ni] = *reinterpret_cast<const half8*>(
            &Bs[r * 64 + ((kk + 8 * (lane >> 4)) ^ ((r & 7) << 3))]);
      }
#pragma unroll
      for (int mi = 0; mi < 2; ++mi)
#pragma unroll
        for (int ni = 0; ni < 4; ++ni)
          acc[mi][ni] =
              __builtin_amdgcn_mfma_f32_16x16x32_f16(af[mi], bf[ni], acc[mi][ni], 0, 0, 0);
    }
    if (more) {
      __syncthreads();
      STORE(it + 1);
    }
    __syncthreads();
  }

  // Fused epilogue (fast exp2/rcp; asymptotes correct)
  const float LOG2E = 1.44269504f;
  const float sz = __builtin_amdgcn_rcpf(1.f + __builtin_amdgcn_exp2f(-zeta[0] * LOG2E));
  const float sn = __builtin_amdgcn_rcpf(1.f + __builtin_amdgcn_exp2f(-nu[0] * LOG2E));
#pragma unroll
  for (int mi = 0; mi < 2; ++mi)
#pragma unroll
    for (int ni = 0; ni < 4; ++ni) {
      const int col = col0 + wc * 64 + ni * 16 + (lane & 15);
      const float bgc = bg[col];
      const float buc = bu[col];
#pragma unroll
      for (int e = 0; e < 4; ++e) {
        const int row = row0 + wr * 32 + mi * 16 + 4 * (lane >> 4) + e;
        const float pre = acc[mi][ni][e];
        const float zg =
            __builtin_amdgcn_rcpf(1.f + __builtin_amdgcn_exp2f(-(pre + bgc) * LOG2E));
        const float hc =
            1.f - 2.f * __builtin_amdgcn_rcpf(
                            1.f + __builtin_amdgcn_exp2f((pre + buc) * (2.f * LOG2E)));
        const float sv = state[(size_t)row * DH + col];
        out[(size_t)row * DH + col] = zg * sv + (sz * (1.f - zg) + sn) * hc;
      }
    }
}

extern "C" void kernel_launch(void* const* d_in, const int* in_sizes, int n_in,
                              void* d_out, int out_size, void* d_ws, size_t ws_size,
                              hipStream_t stream) {
  const float* input = (const float*)d_in[0];
  const float* state = (const float*)d_in[1];
  const float* W1 = (const float*)d_in[2];
  const float* W2 = (const float*)d_in[3];
  const float* U1 = (const float*)d_in[4];
  const float* U2 = (const float*)d_in[5];
  const float* bg = (const float*)d_in[6];
  const float* bu = (const float*)d_in[7];
  const float* zeta = (const float*)d_in[8];
  const float* nu = (const float*)d_in[9];
  float* out = (float*)d_out;

  _Float16* rbuf = (_Float16*)d_ws;                     // 8192*768*2 = 12.6 MB
  _Float16* wb = rbuf + (size_t)8192 * RBLD;            // +3.67 MB f16 weights

  fgrnn_prep<<<1792, 256, 0, stream>>>(W1, U1, W2, U2, wb);
  fgrnn_stage1<<<512, 512, 0, stream>>>(input, state, wb, rbuf);
  fgrnn_stage2<<<2048, 256, 0, stream>>>(rbuf, wb, state, bg, bu, zeta, nu, out);
}